// Round 1
// baseline (178.048 us; speedup 1.0000x reference)
//
#include <hip/hip_runtime.h>

// Problem constants
constexpr int      FRAMES  = 128 * 1024;              // B*T = 131072
constexpr int      FRAME_F = 150;                     // floats per frame
constexpr unsigned NT      = (unsigned)FRAMES * 50u;  // 6,553,600 bone triples
// final = 0.1 * (sum_abs + 0.1*sum_sq) / (FRAMES*150)
constexpr float    SCALE   = 0.1f / ((float)FRAMES * (float)FRAME_F);

constexpr int      BLOCK   = 256;
constexpr int      NBLK    = 2048;                    // 8 blocks/CU
constexpr unsigned STRIDE  = (unsigned)BLOCK * NBLK;  // 524,288 threads
constexpr int      FULL    = NT / STRIDE;             // 12 full grid-strides
// tail: NT - FULL*STRIDE = 262,144 threads do one extra triple (blocks 0..1023)
// STRIDE % 50 == 38, so j advances by 38 (mod 50) per batch; the wrap test
// per batch b reduces to (g % 50) == 49 - (38*b)%50, a compile-time constant.

// One bone triple: thread owns joint j of frame f at flat float offset idx*3.
// Neighbor joint (j+1)%50 is at float offset +3 (or -147 on wrap) — loaded
// directly (adjacent memory, L1-resident: it is lane+1's self triple).
__device__ __forceinline__ float bone_term(const float* __restrict__ ps,
                                           const float* __restrict__ ts,
                                           int no)
{
    const float* pn = ps + no;
    const float* tn = ts + no;

    const float p0 = ps[0], p1 = ps[1], p2 = ps[2];
    const float t0 = ts[0], t1 = ts[1], t2 = ts[2];
    const float q0 = pn[0], q1 = pn[1], q2 = pn[2];
    const float u0 = tn[0], u1 = tn[1], u2 = tn[2];

    // masks: targets*mask == targets identically; mask preds only
    const float m0 = (t0 != 0.0f) ? 1.0f : 0.0f;
    const float m1 = (t1 != 0.0f) ? 1.0f : 0.0f;
    const float m2 = (t2 != 0.0f) ? 1.0f : 0.0f;
    const float n0 = (u0 != 0.0f) ? 1.0f : 0.0f;
    const float n1 = (u1 != 0.0f) ? 1.0f : 0.0f;
    const float n2 = (u2 != 0.0f) ? 1.0f : 0.0f;

    const float pm0 = p0 * m0, pm1 = p1 * m1, pm2 = p2 * m2;
    const float qm0 = q0 * n0, qm1 = q1 * n1, qm2 = q2 * n2;

    // L1 term over this triple
    const float ab = fabsf(pm0 - t0) + fabsf(pm1 - t1) + fabsf(pm2 - t2);

    // bone direction term
    const float pd0 = pm0 - qm0, pd1 = pm1 - qm1, pd2 = pm2 - qm2;
    const float td0 = t0 - u0,   td1 = t1 - u1,   td2 = t2 - u2;

    const float pl2 = pd0*pd0 + pd1*pd1 + pd2*pd2;
    const float tl2 = td0*td0 + td1*td1 + td2*td2;
    // 1/(len+tiny): rsq approximation (rel err ~1e-7), zero-guarded
    const float pri = (pl2 > 0.0f) ? __builtin_amdgcn_rsqf(pl2) : 0.0f;
    const float tri = (tl2 > 0.0f) ? __builtin_amdgcn_rsqf(tl2) : 0.0f;

    const float d0 = pd0 * pri - td0 * tri;
    const float d1 = pd1 * pri - td1 * tri;
    const float d2 = pd2 * pri - td2 * tri;
    const float sq = m0*d0*d0 + m1*d1*d1 + m2*d2*d2;  // mask[:, :, :150] re-mask

    return ab + 0.1f * sq;
}

__global__ __launch_bounds__(BLOCK, 4) void bone_loss_main(
    const float* __restrict__ preds,
    const float* __restrict__ targets,
    float* __restrict__ partials)
{
    const unsigned g  = blockIdx.x * BLOCK + threadIdx.x;
    const unsigned j0 = g % 50u;   // computed once; per-batch wrap is a const compare

    float acc = 0.0f;

    // 12 independent, fully-unrolled batches -> 48 independent dwordx3 loads
    // visible to the scheduler (deep MLP; no cross-batch dependency).
    #pragma unroll
    for (int b = 0; b < FULL; ++b) {
        const unsigned kb  = 49u - (38u * (unsigned)b) % 50u;
        const int      no  = (j0 == kb) ? (3 - FRAME_F) : 3;
        const size_t   e   = (size_t)(g + (unsigned)b * STRIDE) * 3u;
        acc += bone_term(preds + e, targets + e, no);
    }

    // tail batch (b = 12): only first 262,144 threads valid (blocks 0..1023)
    {
        const unsigned idx = g + (unsigned)FULL * STRIDE;
        if (idx < NT) {
            const unsigned kb = 49u - (38u * (unsigned)FULL) % 50u;  // = 43
            const int      no = (j0 == kb) ? (3 - FRAME_F) : 3;
            const size_t   e  = (size_t)idx * 3u;
            acc += bone_term(preds + e, targets + e, no);
        }
    }

    // ---- block reduction ----
    #pragma unroll
    for (int off = 32; off > 0; off >>= 1)
        acc += __shfl_down(acc, off, 64);

    __shared__ float ws[4];
    const int wid = threadIdx.x >> 6;
    if ((threadIdx.x & 63) == 0) ws[wid] = acc;
    __syncthreads();
    if (threadIdx.x == 0)
        partials[blockIdx.x] = ws[0] + ws[1] + ws[2] + ws[3];
}

__global__ __launch_bounds__(256) void bone_loss_finish(
    const float* __restrict__ partials,
    float* __restrict__ out)
{
    float v = 0.0f;
    for (int i = threadIdx.x; i < NBLK; i += 256)
        v += partials[i];

    #pragma unroll
    for (int off = 32; off > 0; off >>= 1)
        v += __shfl_down(v, off, 64);

    __shared__ float ws[4];
    const int wid = threadIdx.x >> 6;
    if ((threadIdx.x & 63) == 0) ws[wid] = v;
    __syncthreads();
    if (threadIdx.x == 0)
        out[0] = (ws[0] + ws[1] + ws[2] + ws[3]) * SCALE;
}

extern "C" void kernel_launch(void* const* d_in, const int* in_sizes, int n_in,
                              void* d_out, int out_size, void* d_ws, size_t ws_size,
                              hipStream_t stream) {
    const float* preds   = (const float*)d_in[0];
    const float* targets = (const float*)d_in[1];
    float* out      = (float*)d_out;
    float* partials = (float*)d_ws;       // NBLK floats = 8 KB

    bone_loss_main<<<NBLK, BLOCK, 0, stream>>>(preds, targets, partials);
    bone_loss_finish<<<1, 256, 0, stream>>>(partials, out);
}